// Round 1
// 150.232 us; speedup vs baseline: 1.0268x; 1.0268x over previous
//
#include <hip/hip_runtime.h>
#include <math.h>

#define NB 2
#define NS 1024
#define NC 1024
#define NH 16
#define DIMP 240
#define KSPLIT 16
#define AKH 16          // attention K-split

constexpr float INV_SQRT3 = 0.57735026919f;
constexpr float LOG2E     = 1.44269504089f;
constexpr float BIAS0     = -23.0831169f;   // -16 * log2(e)
constexpr float BIAS1     = -21.6404252f;   // -15 * log2(e) = BIAS0 + log2(e)

// ---------------- Kernel 1: LN row-stats (wave per row) + w_proj transpose ----------
__global__ __launch_bounds__(256) void pre_kernel(const float* __restrict__ s,
                                                  float2* __restrict__ stats,
                                                  const float* __restrict__ wp,
                                                  float* __restrict__ wt) {
    __shared__ float sh[64 * 61];
    int tid = threadIdx.x;
    if (blockIdx.x < NB * NS / 4) {
        int wave = tid >> 6, lane = tid & 63;
        int row = blockIdx.x * 4 + wave;
        const float4* sp = (const float4*)(s + (size_t)row * NC);
        float sum = 0.0f, sq = 0.0f;
        #pragma unroll
        for (int i = 0; i < 4; i++) {
            float4 v = sp[i * 64 + lane];
            sum += v.x + v.y + v.z + v.w;
            sq  += v.x * v.x + v.y * v.y + v.z * v.z + v.w * v.w;
        }
        #pragma unroll
        for (int off = 32; off; off >>= 1) {
            sum += __shfl_down(sum, off);
            sq  += __shfl_down(sq, off);
        }
        if (lane == 0) {
            float mu  = sum * (1.0f / NC);
            float var = sq * (1.0f / NC) - mu * mu;
            stats[row] = make_float2(mu, rsqrtf(var + 1e-5f));
        }
    } else {
        int bx = blockIdx.x - NB * NS / 4;
        int k0 = (bx & 15) * 64;
        int d0 = (bx >> 4) * 60;
        float (*T)[61] = (float (*)[61])sh;
        #pragma unroll
        for (int i = 0; i < 15; i++) {
            int idx = i * 256 + tid;       // 60d x 64k = 3840
            int dd = idx >> 6, kk = idx & 63;
            T[kk][dd] = wp[(size_t)(d0 + dd) * NC + k0 + kk];
        }
        __syncthreads();
        #pragma unroll
        for (int i = 0; i < 15; i++) {
            int idx = i * 256 + tid;
            int kk = idx / 60, dd = idx % 60;
            wt[(size_t)(k0 + kk) * DIMP + d0 + dd] = T[kk][dd];
        }
    }
}

// ---------------- Kernel 2: proj GEMM, LN applied on LDS-stage, pipelined W ---------
__global__ __launch_bounds__(256) void proj_kernel(const float* __restrict__ s,
                                                   const float2* __restrict__ stats,
                                                   const float* __restrict__ lnw,
                                                   const float* __restrict__ wt,
                                                   float* __restrict__ pp,
                                                   int use_atomic) {
    int tid = threadIdx.x;
    int wave = tid >> 6, lane = tid & 63;
    int row0 = blockIdx.x * 32;
    int ky = blockIdx.y;
    int k0 = ky * 64;

    __shared__ float A[32][64];
    #pragma unroll
    for (int i = 0; i < 2; i++) {
        int idx = tid + i * 256;          // float4 index, 512 total
        int r = idx >> 4, c4 = idx & 15;
        float4 v = *(const float4*)(s + (size_t)(row0 + r) * NC + k0 + c4 * 4);
        float2 st = stats[row0 + r];
        float4 w = *(const float4*)(lnw + k0 + c4 * 4);
        float4 o;
        o.x = (v.x - st.x) * st.y * w.x;
        o.y = (v.y - st.x) * st.y * w.y;
        o.z = (v.z - st.x) * st.y * w.z;
        o.w = (v.w - st.x) * st.y * w.w;
        *(float4*)&A[r][c4 * 4] = o;
    }
    __syncthreads();

    int wr0 = wave * 8;
    int c0 = lane * 4;
    bool active = c0 < DIMP;
    int c0m = active ? c0 : (DIMP - 4);
    const float* wb = wt + (size_t)k0 * DIMP + c0m;

    float acc[8][4];
    #pragma unroll
    for (int r = 0; r < 8; r++)
        #pragma unroll
        for (int c = 0; c < 4; c++) acc[r][c] = 0.0f;

    float4 wa[4], wx[4];
    #pragma unroll
    for (int j = 0; j < 4; j++) wa[j] = *(const float4*)(wb + (size_t)j * DIMP);

    for (int g = 0; g < 16; g += 2) {
        #pragma unroll
        for (int j = 0; j < 4; j++)
            wx[j] = *(const float4*)(wb + (size_t)((g + 1) * 4 + j) * DIMP);
        #pragma unroll
        for (int r = 0; r < 8; r++) {
            float4 a4 = *(const float4*)&A[wr0 + r][g * 4];
            #pragma unroll
            for (int c = 0; c < 4; c++) {
                float* ac = &acc[r][c];
                *ac = fmaf(a4.x, ((const float*)&wa[0])[c], *ac);
                *ac = fmaf(a4.y, ((const float*)&wa[1])[c], *ac);
                *ac = fmaf(a4.z, ((const float*)&wa[2])[c], *ac);
                *ac = fmaf(a4.w, ((const float*)&wa[3])[c], *ac);
            }
        }
        int kn2 = (g + 2 < 16) ? (g + 2) * 4 : 0;
        #pragma unroll
        for (int j = 0; j < 4; j++)
            wa[j] = *(const float4*)(wb + (size_t)(kn2 + j) * DIMP);
        #pragma unroll
        for (int r = 0; r < 8; r++) {
            float4 a4 = *(const float4*)&A[wr0 + r][(g + 1) * 4];
            #pragma unroll
            for (int c = 0; c < 4; c++) {
                float* ac = &acc[r][c];
                *ac = fmaf(a4.x, ((const float*)&wx[0])[c], *ac);
                *ac = fmaf(a4.y, ((const float*)&wx[1])[c], *ac);
                *ac = fmaf(a4.z, ((const float*)&wx[2])[c], *ac);
                *ac = fmaf(a4.w, ((const float*)&wx[3])[c], *ac);
            }
        }
    }
    if (active) {
        if (use_atomic) {
            #pragma unroll
            for (int r = 0; r < 8; r++)
                #pragma unroll
                for (int c = 0; c < 4; c++)
                    atomicAdd(&pp[(size_t)(row0 + wr0 + r) * DIMP + c0 + c], acc[r][c]);
        } else {
            float* dst = pp + (size_t)ky * (NB * NS * DIMP);
            #pragma unroll
            for (int r = 0; r < 8; r++)
                *(float4*)(dst + (size_t)(row0 + wr0 + r) * DIMP + c0) =
                    make_float4(acc[r][0], acc[r][1], acc[r][2], acc[r][3]);
        }
    }
}

// ---------------- Kernel 3: partial-sum + rotate + scale-fold (log2 domain) + pack --
// kpack record per (b,h,k), 3 float4s: f0=(kr.xyz, ck) f1=(kd.xyz, sk) f2=(vv.xyz, 0)
__global__ __launch_bounds__(256) void build_kernel(const float* __restrict__ pp, int nred,
                                                    const float* __restrict__ rot,
                                                    const float* __restrict__ trans,
                                                    const float* __restrict__ dist_scale,
                                                    const float* __restrict__ rot_scale,
                                                    const int* __restrict__ seq,
                                                    const int* __restrict__ chain,
                                                    const int* __restrict__ amask,
                                                    float4* __restrict__ qrb,
                                                    float4* __restrict__ qdb,
                                                    float4* __restrict__ kp) {
    int gid = blockIdx.x * 256 + threadIdx.x;   // NB*NS*80
    if (gid >= NB * NS * 80) return;
    int j  = gid % 80;
    int bs = gid / 80;
    int b  = bs >> 10;
    int si = bs & 1023;
    int off = (j < 48) ? 3 * j : 144 + 3 * (j - 48);
    float vx = 0.0f, vy = 0.0f, vz = 0.0f;
    for (int ky = 0; ky < nred; ky++) {
        const float* pr = pp + (size_t)ky * (NB * NS * DIMP) + (size_t)bs * DIMP + off;
        vx += pr[0]; vy += pr[1]; vz += pr[2];
    }
    const float* R = rot + (size_t)bs * 9;
    float ox = R[0] * vx + R[1] * vy + R[2] * vz;
    float oy = R[3] * vx + R[4] * vy + R[5] * vz;
    float oz = R[6] * vx + R[7] * vy + R[8] * vz;
    if (j >= 48) {
        ox += trans[(size_t)bs * 3 + 0];
        oy += trans[(size_t)bs * 3 + 1];
        oz += trans[(size_t)bs * 3 + 2];
    }
    if (j < 16) {
        float sc = log1pf(__expf(rot_scale[j])) * INV_SQRT3 * LOG2E;
        qrb[(size_t)(b * NH + j) * NS + si] = make_float4(ox * sc, oy * sc, oz * sc, 0.0f);
    } else if (j < 32) {
        int h = j - 16;
        float ck = (float)chain[bs] + 1000.0f * (float)(1 - amask[bs]);
        kp[((size_t)(b * NH + h) * NS + si) * 3 + 0] = make_float4(ox, oy, oz, ck);
    } else if (j < 48) {
        int h = j - 32;
        kp[((size_t)(b * NH + h) * NS + si) * 3 + 2] = make_float4(ox, oy, oz, 0.0f);
    } else if (j < 64) {
        int h = j - 48;
        float sc = log1pf(__expf(dist_scale[h])) * INV_SQRT3 * LOG2E;
        qdb[(size_t)(b * NH + h) * NS + si] = make_float4(ox * sc, oy * sc, oz * sc, 0.0f);
    } else {
        int h = j - 64;
        float sc = log1pf(__expf(dist_scale[h])) * INV_SQRT3 * LOG2E;
        kp[((size_t)(b * NH + h) * NS + si) * 3 + 1] =
            make_float4(ox * sc, oy * sc, oz * sc, (float)seq[bs]);
    }
}

// ---------------- Kernel 4: attention — lane-owns-q, 16-way K-split, exp2 domain ----
// grid: 32 bh x 4 qc x AKH ks = 2048 blocks, 256 thr. LDS: 64 k-records (3 KB).
__global__ __launch_bounds__(256) void attn_kernel(
    const float4* __restrict__ qrb, const float4* __restrict__ qdb,
    const float4* __restrict__ kp,
    float4* __restrict__ pacc) {
    __shared__ float4 kS[192];
    int bx = blockIdx.x;
    int ks = bx & (AKH - 1), qc = (bx >> 4) & 3, bh = bx >> 6;
    int tid = threadIdx.x;
    int q = qc * 256 + tid;
    int base = bh * NS;
    const float4* kb = kp + (size_t)base * 3;

    if (tid < 192) kS[tid] = kb[(size_t)ks * 192 + tid];
    __syncthreads();

    float4 a = qrb[base + q];
    float4 d = qdb[base + q];
    float cq = kb[(size_t)q * 3 + 0].w;
    float sq = kb[(size_t)q * 3 + 1].w;

    float l = 0.0f, ax = 0.0f, ay = 0.0f, az = 0.0f;
    #pragma unroll 4
    for (int j = 0; j < 64; j++) {
        float4 f0 = kS[j * 3 + 0];
        float4 f1 = kS[j * 3 + 1];
        float4 f2 = kS[j * 3 + 2];
        float rt = fmaf(a.x, f0.x, fmaf(a.y, f0.y, a.z * f0.z));
        float dx = d.x - f1.x, dy = d.y - f1.y, dz = d.z - f1.z;
        float dist = __builtin_amdgcn_sqrtf(fmaf(dx, dx, fmaf(dy, dy, dz * dz)));
        float dc = f0.w - cq;
        float arg = fmaf(-100.0f, fabsf(dc), rt - dist) +
                    ((f1.w == sq) ? BIAS1 : BIAS0);
        float pw = exp2f(arg);   // masked (|dc|>=1) underflows to 0
        l += pw;
        ax = fmaf(pw, f2.x, ax);
        ay = fmaf(pw, f2.y, ay);
        az = fmaf(pw, f2.z, az);
    }
    pacc[(size_t)ks * (32 * NS) + base + q] = make_float4(ax, ay, az, l);
}

// ---------------- Kernel 5: fused finalize + out GEMM ------------------------------
// grid: 256 blocks x 256 thr; block owns 8 (b,q) rows.
// phase 1 (128 thr): sum AKH partials, divide, R^T rotate, mask -> sm[8][48]
// phase 2 (256 thr): out[row][c] = sum_d sm[row][d] * wout[c][d], c looped x4
__global__ __launch_bounds__(256) void finout_kernel(const float4* __restrict__ pacc,
                                                     const float4* __restrict__ kp,
                                                     const float* __restrict__ rot,
                                                     const float* __restrict__ wout,
                                                     float* __restrict__ out) {
    __shared__ float sm[8][48];
    int tid = threadIdx.x;
    int r0 = blockIdx.x * 8;                    // base (b*NS+q) row index
    if (tid < 128) {
        int r = tid & 7, h = tid >> 3;
        int bq = r0 + r;
        int b = bq >> 10, q = bq & 1023;
        int i = (b * NH + h) * NS + q;
        float sx = 0.0f, sy = 0.0f, sz = 0.0f, sw = 0.0f;
        #pragma unroll
        for (int j = 0; j < AKH; j++) {
            float4 t = pacc[(size_t)j * (NB * NH * NS) + i];
            sx += t.x; sy += t.y; sz += t.z; sw += t.w;
        }
        float inv = 1.0f / sw;
        float ox = sx * inv, oy = sy * inv, oz = sz * inv;
        const float* R = rot + (size_t)bq * 9;
        float wxv = R[0] * ox + R[3] * oy + R[6] * oz;
        float wyv = R[1] * ox + R[4] * oy + R[7] * oz;
        float wzv = R[2] * ox + R[5] * oy + R[8] * oz;
        float cq = kp[(size_t)i * 3].w;
        if (cq >= 500.0f) { wxv = 0; wyv = 0; wzv = 0; }   // am_q == 0
        sm[r][h * 3 + 0] = wxv;
        sm[r][h * 3 + 1] = wyv;
        sm[r][h * 3 + 2] = wzv;
    }
    __syncthreads();
    #pragma unroll 1
    for (int ch = 0; ch < 4; ch++) {
        int c = ch * 256 + tid;
        float w[48];
        #pragma unroll
        for (int d = 0; d < 48; d += 4) {
            float4 t = *(const float4*)(wout + (size_t)c * 48 + d);
            w[d] = t.x; w[d + 1] = t.y; w[d + 2] = t.z; w[d + 3] = t.w;
        }
        #pragma unroll 4
        for (int r = 0; r < 8; r++) {
            float acc = 0.0f;
            #pragma unroll
            for (int d = 0; d < 48; d++) acc = fmaf(w[d], sm[r][d], acc);
            out[(size_t)(r0 + r) * NC + c] = acc;
        }
    }
}

extern "C" void kernel_launch(void* const* d_in, const int* in_sizes, int n_in,
                              void* d_out, int out_size, void* d_ws, size_t ws_size,
                              hipStream_t stream) {
    const float* s     = (const float*)d_in[0];
    const float* rot   = (const float*)d_in[1];
    const float* trans = (const float*)d_in[2];
    const float* lnw   = (const float*)d_in[3];
    const float* wproj = (const float*)d_in[4];
    const float* wout  = (const float*)d_in[5];
    const float* dsc   = (const float*)d_in[6];
    const float* rsc   = (const float*)d_in[7];
    const int* amask   = (const int*)d_in[8];
    const int* seq     = (const int*)d_in[9];
    const int* chain   = (const int*)d_in[10];
    float* out = (float*)d_out;

    // ws layout (floats): stats[4096] | qrb[131072] | qdb[131072] | kp[393216] |
    //                     pp[KSPLIT x 491520]   ~= 34 MB
    // wt (983 KB) overlays qrb+qdb (dead before build writes them);
    // pacc (8 MB) overlays pp (dead after build).
    float2* stats = (float2*)d_ws;
    float4* qrb = (float4*)((float*)d_ws + 4096);
    float4* qdb = qrb + (size_t)NB * NH * NS;
    float4* kpk = qdb + (size_t)NB * NH * NS;
    float* pp = (float*)(kpk + (size_t)3 * NB * NH * NS);
    float* wt = (float*)qrb;
    float4* pacc = (float4*)pp;

    size_t need = ((char*)(pp + (size_t)KSPLIT * NB * NS * DIMP)) - (char*)d_ws;
    int use_atomic = (ws_size < need) ? 1 : 0;

    pre_kernel<<<NB * NS / 4 + 64, 256, 0, stream>>>(s, stats, wproj, wt);
    if (use_atomic) {
        hipMemsetAsync(pp, 0, (size_t)NB * NS * DIMP * sizeof(float), stream);
        proj_kernel<<<dim3(64, KSPLIT), 256, 0, stream>>>(s, stats, lnw, wt, pp, 1);
        build_kernel<<<(NB * NS * 80 + 255) / 256, 256, 0, stream>>>(pp, 1, rot, trans, dsc, rsc,
                                                                     seq, chain, amask, qrb, qdb, kpk);
    } else {
        proj_kernel<<<dim3(64, KSPLIT), 256, 0, stream>>>(s, stats, lnw, wt, pp, 0);
        build_kernel<<<(NB * NS * 80 + 255) / 256, 256, 0, stream>>>(pp, KSPLIT, rot, trans, dsc, rsc,
                                                                     seq, chain, amask, qrb, qdb, kpk);
    }
    attn_kernel<<<NB * NH * 4 * AKH, 256, 0, stream>>>(qrb, qdb, kpk, pacc);
    finout_kernel<<<NB * NS / 8, 256, 0, stream>>>(pacc, kpk, rot, wout, out);
}